// Round 25
// baseline (298.841 us; speedup 1.0000x reference)
//
#include <hip/hip_runtime.h>
#include <hip/hip_bf16.h>
#include <hip/hip_fp16.h>
#include <math.h>

// Problem constants
#define BB 4
#define NN 4096
#define EE 256
#define HH 1024
#define NW 12
#define NL 13
#define MM (BB * NN)   // 16384 rows

typedef __attribute__((ext_vector_type(8))) short short8;   // 8x16b (4 VGPRs)
typedef __attribute__((ext_vector_type(4))) float f32x4;
typedef __attribute__((ext_vector_type(2))) _Float16 h2;    // packed f16 pair
typedef __attribute__((ext_vector_type(8))) _Float16 half8; // f16 MFMA frag

// Fast gelu, f32 scalar: x*sigmoid(1.5957691(x+0.044715x^3)), exp2 form.
__device__ __forceinline__ float gelu_fast(float x) {
    float t = __builtin_fmaf(0.044715f, x * x, 1.0f);
    float e = __builtin_amdgcn_exp2f(-2.3021193f * (x * t));
    return x * __builtin_amdgcn_rcpf(1.0f + e);
}

// Packed-f16 gelu on a pair of f32 inputs -> packed f16 pair bits (r15: -7us).
__device__ __forceinline__ unsigned gelu2_f16(float a, float b) {
    const h2 C1 = {(_Float16)-2.3021193f, (_Float16)-2.3021193f};
    const h2 C2 = {(_Float16)0.044715f, (_Float16)0.044715f};
    const h2 ONE = {(_Float16)1.0f, (_Float16)1.0f};
    h2 x;
    asm("v_cvt_pkrtz_f16_f32 %0, %1, %2" : "=v"(x) : "v"(a), "v"(b));
    h2 x2 = x * x;
    h2 t  = C2 * x2 + ONE;          // v_pk_fma_f16
    h2 z  = (C1 * x) * t;
    __half2 es = h2exp2(__builtin_bit_cast(__half2, z));
    h2 d = ONE + __builtin_bit_cast(h2, es);
    __half2 rs = h2rcp(__builtin_bit_cast(__half2, d));
    h2 y = x * __builtin_bit_cast(h2, rs);
    return __builtin_bit_cast(unsigned, y);
}

// HW packed f32->2xf16 (RTZ), 1 VALU op.
__device__ __forceinline__ h2 cvt_pk_f16(float a, float b) {
    h2 r;
    asm("v_cvt_pkrtz_f16_f32 %0, %1, %2" : "=v"(r) : "v"(a), "v"(b));
    return r;
}

// HW packed f32->2xbf16 (RNE), 1 VALU op.
__device__ __forceinline__ unsigned cvt_pk_bf16(float a, float b) {
    unsigned r;
    asm("v_cvt_pk_bf16_f32 %0, %1, %2" : "=v"(r) : "v"(a), "v"(b));
    return r;
}

__device__ __forceinline__ void load_lds16(const void* g, void* l) {
    __builtin_amdgcn_global_load_lds(
        (const __attribute__((address_space(1))) void*)g,
        (__attribute__((address_space(3))) void*)l, 16, 0, 0);
}

// ---------------------------------------------------------------------------
// Gate gemm2 (K=1024), BN=64 tile, 2 blocks/CU (r22-validated ~16us).
// ---------------------------------------------------------------------------
__global__ __launch_bounds__(256) void gemm2_bn64(
    const __hip_bfloat16* __restrict__ A,   // MM x HH (Whb)
    const __hip_bfloat16* __restrict__ Bt,  // EE x HH (gW2t)
    const float* __restrict__ bias,         // EE
    _Float16* __restrict__ C)               // MM x EE (f16 state)
{
    __shared__ __hip_bfloat16 As[128 * 32];     // 8 KB
    __shared__ __hip_bfloat16 Bs[64 * 32];      // 4 KB

    const int tid = threadIdx.x;
    const int w = tid >> 6, l = tid & 63;
    const int wr = w >> 1, wc = w & 1;          // 2x2; wave tile 64r x 32c
    const int row0 = blockIdx.y * 128;
    const int col0 = blockIdx.x * 64;

    const int c0 = w * 64 + l;
    const int c1 = c0 + 256;
    const __hip_bfloat16* gA0 = A  + (size_t)(row0 + (c0 >> 2)) * HH + (c0 & 3) * 8;
    const __hip_bfloat16* gA1 = A  + (size_t)(row0 + (c1 >> 2)) * HH + (c1 & 3) * 8;
    const __hip_bfloat16* gB0 = Bt + (size_t)(col0 + (c0 >> 2)) * HH + (c0 & 3) * 8;
    char* dA0 = (char*)As + c0 * 16;
    char* dA1 = (char*)As + c1 * 16;
    char* dB0 = (char*)Bs + c0 * 16;

    const int lr = l & 15;
    const int lk = (l >> 4) * 8;

    f32x4 acc[4][2] = {};

    for (int k0 = 0; k0 < HH; k0 += 32) {
        load_lds16(gA0 + k0, dA0);
        load_lds16(gA1 + k0, dA1);
        load_lds16(gB0 + k0, dB0);
        __syncthreads();

        short8 a[4], b[2];
        #pragma unroll
        for (int m = 0; m < 4; ++m)
            a[m] = *(const short8*)&As[(wr * 64 + m * 16 + lr) * 32 + lk];
        #pragma unroll
        for (int n = 0; n < 2; ++n)
            b[n] = *(const short8*)&Bs[(wc * 32 + n * 16 + lr) * 32 + lk];
        #pragma unroll
        for (int m = 0; m < 4; ++m)
            #pragma unroll
            for (int n = 0; n < 2; ++n)
                acc[m][n] = __builtin_amdgcn_mfma_f32_16x16x32_bf16(a[m], b[n], acc[m][n], 0, 0, 0);
        __syncthreads();
    }

    #pragma unroll
    for (int m = 0; m < 4; ++m) {
        #pragma unroll
        for (int n = 0; n < 2; ++n) {
            const int col = col0 + wc * 32 + n * 16 + lr;
            const float bv = bias[col];
            #pragma unroll
            for (int j = 0; j < 4; ++j) {
                const int row = row0 + wr * 64 + m * 16 + (l >> 4) * 4 + j;
                C[(size_t)row * EE + col] = (_Float16)(acc[m][n][j] + bv);
            }
        }
    }
}

// ---------------------------------------------------------------------------
// Gate gemm1, A-in-registers (r14/r16-validated): Wh(bf16) = gelu(Vb@W1+b1).
// ---------------------------------------------------------------------------
__global__ __launch_bounds__(256, 3) void gemm1_areg(
    const __hip_bfloat16* __restrict__ A,     // MM x EE (Vb)
    const __hip_bfloat16* __restrict__ W1t,   // HH x EE
    const float* __restrict__ b1,             // HH
    __hip_bfloat16* __restrict__ Wh)          // MM x HH
{
    __shared__ __hip_bfloat16 Bs[8 * 64 * 32];   // 32 KB [kk][row][32]
    __shared__ __align__(16) char Gb[4][4096];   // per-wave G [32r][64h]

    const int tid = threadIdx.x;
    const int w = tid >> 6, l = tid & 63;
    const int row0 = blockIdx.x * 128;
    const int col0 = blockIdx.y * 128;
    const int lr = l & 15, g = l >> 4, lk = g * 8;

    short8 xf[2][8];
    {
        const __hip_bfloat16* xp0 = A + (size_t)(row0 + w * 32 + lr) * EE + lk;
        #pragma unroll
        for (int kk = 0; kk < 8; ++kk) {
            xf[0][kk] = *(const short8*)(xp0 + kk * 32);
            xf[1][kk] = *(const short8*)(xp0 + 16 * EE + kk * 32);
        }
    }
    char* Gw = Gb[w];

    #pragma unroll
    for (int rstep = 0; rstep < 8; ++rstep) {
        const int c = rstep * 256 + tid;
        load_lds16(W1t + (size_t)(col0 + ((c >> 2) & 63)) * EE + (c >> 8) * 32 + (c & 3) * 8,
                   (char*)Bs + c * 16);
    }
    __syncthreads();

    #pragma unroll 1
    for (int ct = 0; ct < 2; ++ct) {
        f32x4 acc[4][2];
        #pragma unroll
        for (int ni = 0; ni < 4; ++ni) {
            const float4 bv = *(const float4*)&b1[col0 + ct * 64 + ni * 16 + g * 4];
            const f32x4 bi = {bv.x, bv.y, bv.z, bv.w};
            acc[ni][0] = bi;
            acc[ni][1] = bi;
        }
        __builtin_amdgcn_s_setprio(1);
        #pragma unroll
        for (int kk = 0; kk < 8; ++kk) {
            short8 a[4];
            #pragma unroll
            for (int ni = 0; ni < 4; ++ni)
                a[ni] = *(const short8*)((const char*)Bs +
                         (kk * 4096 + ni * 1024 + lr * 64 + g * 16));
            #pragma unroll
            for (int ni = 0; ni < 4; ++ni) {
                acc[ni][0] = __builtin_amdgcn_mfma_f32_16x16x32_bf16(a[ni], xf[0][kk], acc[ni][0], 0, 0, 0);
                acc[ni][1] = __builtin_amdgcn_mfma_f32_16x16x32_bf16(a[ni], xf[1][kk], acc[ni][1], 0, 0, 0);
            }
        }
        __builtin_amdgcn_s_setprio(0);
        __syncthreads();

        if (ct == 0) {
            #pragma unroll
            for (int rstep = 0; rstep < 8; ++rstep) {
                const int c = rstep * 256 + tid;
                load_lds16(W1t + (size_t)(col0 + 64 + ((c >> 2) & 63)) * EE + (c >> 8) * 32 + (c & 3) * 8,
                           (char*)Bs + c * 16);
            }
        }

        // gelu (f32) -> bf16 (cvt_pk) -> wave-private swizzled G
        #pragma unroll
        for (int ni = 0; ni < 4; ++ni) {
            #pragma unroll
            for (int mi = 0; mi < 2; ++mi) {
                const int rloc = mi * 16 + lr;
                const float v0 = gelu_fast(acc[ni][mi][0]);
                const float v1 = gelu_fast(acc[ni][mi][1]);
                const float v2 = gelu_fast(acc[ni][mi][2]);
                const float v3 = gelu_fast(acc[ni][mi][3]);
                uint2 pk;
                pk.x = cvt_pk_bf16(v0, v1);
                pk.y = cvt_pk_bf16(v2, v3);
                const int byte = (rloc * 128 + (ni * 16 + g * 4) * 2) ^ ((rloc & 7) << 4);
                *(uint2*)(Gw + byte) = pk;
            }
        }

        // coalesced store: 4 passes x (8 rows x 128B); G is wave-private
        #pragma unroll
        for (int p = 0; p < 4; ++p) {
            const int rl = p * 8 + (l >> 3);
            const int hb = (l & 7) * 16;
            const uint4 v = *(const uint4*)(Gw + ((rl * 128 + hb) ^ ((rl & 7) << 4)));
            *(uint4*)((char*)(Wh + (size_t)(row0 + w * 32 + rl) * HH + col0 + ct * 64) + hb) = v;
        }
        __syncthreads();
    }
}

// ---------------------------------------------------------------------------
// Fused f-level kernel v6: 16x16 MFMA big GEMM (r22/r24-validated), gelu
// packed-f16, mini-GEMM f16, packed-f16 Wall epilogue (r24).
// LDS cut to 40 KB (Bs 32K + half-G 8K; bias read from global like gemm1)
// -> 4 blocks/CU (was 3). G processed in two 32-h halves; the 64-B-row
// half-G is bank-balanced for b128 reads (8 acc/bank = minimum).
// ---------------------------------------------------------------------------
__global__ __launch_bounds__(256, 4) void f_fused(
    const __hip_bfloat16* __restrict__ X,     // MM x EE (bf16)
    const __hip_bfloat16* __restrict__ W1t,   // NW x HH x EE (bf16)
    const float* __restrict__ b1,             // NW x HH
    const _Float16* __restrict__ W2t,         // NW x 16 x HH (f16)
    const float* __restrict__ b2,             // NW x NL
    unsigned* __restrict__ Wall_u)            // [NW*16][MM] packed f16 pairs
{
    __shared__ __hip_bfloat16 Bs[8 * 64 * 32];        // 32 KB [kk][row][32]
    __shared__ __align__(16) char Gb[4][2048];        // per-wave G [32r][32h] f16

    const int tid = threadIdx.x;
    const int w = tid >> 6, l = tid & 63;
    const int row0 = blockIdx.x * 128;
    const int m_lv = blockIdx.y;
    const int lr = l & 15;
    const int g  = l >> 4;
    const int lk = g * 8;

    const __hip_bfloat16* W1m = W1t + (size_t)m_lv * HH * EE;
    const float* b1m = b1 + (size_t)m_lv * HH;

    short8 xf[2][8];
    {
        const __hip_bfloat16* xp0 = X + (size_t)(row0 + w * 32 + lr) * EE + lk;
        #pragma unroll
        for (int kk = 0; kk < 8; ++kk) {
            xf[0][kk] = *(const short8*)(xp0 + kk * 32);
            xf[1][kk] = *(const short8*)(xp0 + 16 * EE + kk * 32);
        }
    }

    const _Float16* w2p = W2t + ((size_t)m_lv * 16 + lr) * HH + lk;
    char* Gw = Gb[w];

    f32x4 wacc0 = {}, wacc1 = {};

    #pragma unroll
    for (int rstep = 0; rstep < 8; ++rstep) {
        const int c = rstep * 256 + tid;
        load_lds16(W1m + (size_t)((c >> 2) & 63) * EE + (c >> 8) * 32 + (c & 3) * 8,
                   (char*)Bs + c * 16);
    }
    __syncthreads();

    #pragma unroll 1
    for (int ct = 0; ct < 16; ++ct) {
        // acc C-in = bias (from global; L2-resident 4 KB per level)
        f32x4 acc[4][2];
        #pragma unroll
        for (int ni = 0; ni < 4; ++ni) {
            const float4 bv = *(const float4*)&b1m[ct * 64 + ni * 16 + g * 4];
            const f32x4 bi = {bv.x, bv.y, bv.z, bv.w};
            acc[ni][0] = bi;
            acc[ni][1] = bi;
        }
        __builtin_amdgcn_s_setprio(1);
        #pragma unroll
        for (int kk = 0; kk < 8; ++kk) {
            short8 a[4];
            #pragma unroll
            for (int ni = 0; ni < 4; ++ni)
                a[ni] = *(const short8*)((const char*)Bs +
                         (kk * 4096 + ni * 1024 + lr * 64 + g * 16));
            #pragma unroll
            for (int ni = 0; ni < 4; ++ni) {
                acc[ni][0] = __builtin_amdgcn_mfma_f32_16x16x32_bf16(a[ni], xf[0][kk], acc[ni][0], 0, 0, 0);
                acc[ni][1] = __builtin_amdgcn_mfma_f32_16x16x32_bf16(a[ni], xf[1][kk], acc[ni][1], 0, 0, 0);
            }
        }
        __builtin_amdgcn_s_setprio(0);
        __syncthreads();                       // all waves done reading Bs

        if (ct < 15) {
            const __hip_bfloat16* W1n = W1m + (size_t)(ct + 1) * 64 * EE;
            #pragma unroll
            for (int rstep = 0; rstep < 8; ++rstep) {
                const int c = rstep * 256 + tid;
                load_lds16(W1n + (size_t)((c >> 2) & 63) * EE + (c >> 8) * 32 + (c & 3) * 8,
                           (char*)Bs + c * 16);
            }
        }

        // two 32-h halves: gelu -> half-G -> one ks2 of the mini-GEMM each
        #pragma unroll
        for (int half = 0; half < 2; ++half) {
            #pragma unroll
            for (int nl2 = 0; nl2 < 2; ++nl2) {
                const int ni = half * 2 + nl2;
                #pragma unroll
                for (int mi = 0; mi < 2; ++mi) {
                    const int rloc = mi * 16 + lr;
                    uint2 pk;
                    pk.x = gelu2_f16(acc[ni][mi][0], acc[ni][mi][1]);
                    pk.y = gelu2_f16(acc[ni][mi][2], acc[ni][mi][3]);
                    *(uint2*)(Gw + (rloc * 64 + nl2 * 32 + g * 8)) = pk;
                }
            }
            const half8 aw = *(const half8*)(w2p + ct * 64 + half * 32);
            {
                const half8 bg = *(const half8*)(Gw + (lr * 64 + g * 16));
                wacc0 = __builtin_amdgcn_mfma_f32_16x16x32_f16(aw, bg, wacc0, 0, 0, 0);
            }
            {
                const half8 bg = *(const half8*)(Gw + ((16 + lr) * 64 + g * 16));
                wacc1 = __builtin_amdgcn_mfma_f32_16x16x32_f16(aw, bg, wacc1, 0, 0, 0);
            }
        }
        __syncthreads();                       // staging drained; Bs ready
    }

    // epilogue -> Wall_u[(m*16 + lval)*MM + r] as duplicated packed f16
    const float* b2m = b2 + m_lv * NL;
    #pragma unroll
    for (int j = 0; j < 4; ++j) {
        const int lval = g * 4 + j;
        const float bv = (lval < NL) ? b2m[lval] : 0.f;
        unsigned* wp = Wall_u + (size_t)(m_lv * 16 + lval) * MM;
        const float v0 = wacc0[j] + bv;
        const float v1 = wacc1[j] + bv;
        wp[row0 + w * 32 + lr]      = __builtin_bit_cast(unsigned, cvt_pk_f16(v0, v0));
        wp[row0 + w * 32 + 16 + lr] = __builtin_bit_cast(unsigned, cvt_pk_f16(v1, v1));
    }
}

// ---------------------------------------------------------------------------
// One prep kernel for ALL conversions/transposes.
// ---------------------------------------------------------------------------
struct bf4 { __hip_bfloat16 a, b, c, d; };

__device__ __forceinline__ void cvt_body(
    const float* __restrict__ in, __hip_bfloat16* __restrict__ out, int i)
{
    float4 v = ((const float4*)in)[i];
    bf4 o;
    o.a = __float2bfloat16(v.x); o.b = __float2bfloat16(v.y);
    o.c = __float2bfloat16(v.z); o.d = __float2bfloat16(v.w);
    ((bf4*)out)[i] = o;
}

__device__ __forceinline__ void transpose_body(
    const float* __restrict__ inB, __hip_bfloat16* __restrict__ outB,
    int K, int N, int bx, int by, float (*t)[33])
{
    const int n0 = bx * 32, k0 = by * 32;
    const int tx = threadIdx.x & 31, ty = threadIdx.x >> 5;  // 32 x 8
    #pragma unroll
    for (int i = 0; i < 32; i += 8)
        t[ty + i][tx] = inB[(size_t)(k0 + ty + i) * N + n0 + tx];
    __syncthreads();
    #pragma unroll
    for (int i = 0; i < 32; i += 8)
        outB[(size_t)(n0 + ty + i) * K + k0 + tx] = __float2bfloat16(t[tx][ty + i]);
}

__global__ __launch_bounds__(256) void prep_all(
    const float* __restrict__ V, const float* __restrict__ input,
    const float* __restrict__ g_W1, const float* __restrict__ g_W2,
    const float* __restrict__ f_W1, const float* __restrict__ f_W2,
    __hip_bfloat16* __restrict__ Vb, __hip_bfloat16* __restrict__ Xb,
    __hip_bfloat16* __restrict__ gW1t, __hip_bfloat16* __restrict__ gW2t,
    __hip_bfloat16* __restrict__ fW1t, _Float16* __restrict__ W2tA)
{
    __shared__ float t[32][33];
    const int bid = blockIdx.x;
    const int tid = threadIdx.x;

    if (bid < 4096) {
        cvt_body(V, Vb, bid * 256 + tid);
    } else if (bid < 8192) {
        cvt_body(input, Xb, (bid - 4096) * 256 + tid);
    } else if (bid < 8448) {
        const int b2 = bid - 8192;                   // g_W1: grid (32, 8)
        transpose_body(g_W1, gW1t, EE, HH, b2 & 31, b2 >> 5, t);
    } else if (bid < 8704) {
        const int b2 = bid - 8448;                   // g_W2: grid (8, 32)
        transpose_body(g_W2, gW2t, HH, EE, b2 & 7, b2 >> 3, t);
    } else if (bid < 11776) {
        const int b2 = bid - 8704;                   // f_W1: 12 x (32, 8)
        const int z = b2 >> 8, r = b2 & 255;
        transpose_body(f_W1 + (size_t)z * EE * HH, fW1t + (size_t)z * HH * EE,
                       EE, HH, r & 31, r >> 5, t);
    } else {
        const int idx = (bid - 11776) * 256 + tid;   // w2t: NW*16*HH elems, f16
        const int m = idx >> 14;
        const int n = (idx >> 10) & 15;
        const int h = idx & 1023;
        const float v = (n < NL) ? f_W2[((size_t)m * HH + h) * NL + n] : 0.f;
        W2tA[idx] = (_Float16)v;
    }
}

// ---------------------------------------------------------------------------
// ALL 12 chord steps in ONE kernel, PACKED-F16 state resident in LDS
// (r21/r22/r24-validated). Weights pre-packed (duplicated f16 pair per uint).
// ---------------------------------------------------------------------------
__global__ __launch_bounds__(1024, 1) void chord_lds(
    const uint2* __restrict__ Vg,       // MM x 64 (2x packed-f16 per slot)
    const unsigned* __restrict__ Wall_u,// [NW*16][MM] packed f16 pairs
    float4* __restrict__ outF)          // MM x 64 (f32 x4) final output
{
    __shared__ unsigned L[2][2][NN];   // [buf][ch-pair][row]  64 KB

    const int tid = threadIdx.x;       // 0..1023
    const int bid = blockIdx.x;        // 0..255
    const int batch = bid >> 6;
    const int slice = bid & 63;        // 4-channel slice
    const int gbase = batch * NN;

    // init: load own 4 rows from global (f16 x4 per row, already packed)
    #pragma unroll
    for (int i = 0; i < 4; ++i) {
        const int n = tid + i * 1024;
        const uint2 u = Vg[(size_t)(gbase + n) * 64 + slice];
        L[0][0][n] = u.x;
        L[0][1][n] = u.y;
    }
    __syncthreads();

    int cur = 0;
    #pragma unroll 1
    for (int m = 0; m < NW; ++m) {
        const unsigned* wbase = Wall_u + (size_t)m * 16 * MM + gbase;
        const int nxt = cur ^ 1;
        #pragma unroll 1
        for (int i = 0; i < 4; ++i) {
            const int n = tid + i * 1024;
            h2 a01 = __builtin_bit_cast(h2, L[cur][0][n]);
            h2 a23 = __builtin_bit_cast(h2, L[cur][1][n]);
            #pragma unroll
            for (int l = 0; l < NL; ++l) {
                const int off = (l == 0) ? 0 : (1 << (l - 1));
                const int cn = (n + off) & (NN - 1);
                const h2 w2 = __builtin_bit_cast(h2, wbase[(size_t)l * MM + n]);
                const h2 x01 = __builtin_bit_cast(h2, L[cur][0][cn]);
                const h2 x23 = __builtin_bit_cast(h2, L[cur][1][cn]);
                a01 = w2 * x01 + a01;          // v_pk_fma_f16
                a23 = w2 * x23 + a23;
            }
            if (m == NW - 1) {
                float4 o = {(float)a01[0], (float)a01[1],
                            (float)a23[0], (float)a23[1]};
                outF[(size_t)(gbase + n) * 64 + slice] = o;
            } else {
                L[nxt][0][n] = __builtin_bit_cast(unsigned, a01);
                L[nxt][1][n] = __builtin_bit_cast(unsigned, a23);
            }
        }
        __syncthreads();
        cur ^= 1;
    }
}

// ---------------------------------------------------------------------------
extern "C" void kernel_launch(void* const* d_in, const int* in_sizes, int n_in,
                              void* d_out, int out_size, void* d_ws, size_t ws_size,
                              hipStream_t stream)
{
    const float* V      = (const float*)d_in[0];
    const float* input  = (const float*)d_in[1];
    const float* g_W1   = (const float*)d_in[2];
    const float* g_b1   = (const float*)d_in[3];
    const float* g_W2   = (const float*)d_in[4];
    const float* g_b2   = (const float*)d_in[5];
    const float* f_W1   = (const float*)d_in[6];
    const float* f_b1   = (const float*)d_in[7];
    const float* f_W2   = (const float*)d_in[8];
    const float* f_b2   = (const float*)d_in[9];
    float* out = (float*)d_out;

    char* ws = (char*)d_ws;
    size_t o = 0;
    __hip_bfloat16* Vb     = (__hip_bfloat16*)(ws + o); o += (size_t)MM * EE * 2;        // 8 MB
    __hip_bfloat16* Xb     = (__hip_bfloat16*)(ws + o); o += (size_t)MM * EE * 2;        // 8 MB
    __hip_bfloat16* gW1t   = (__hip_bfloat16*)(ws + o); o += (size_t)HH * EE * 2;        // 512 KB
    __hip_bfloat16* gW2t   = (__hip_bfloat16*)(ws + o); o += (size_t)EE * HH * 2;        // 512 KB
    __hip_bfloat16* fW1t   = (__hip_bfloat16*)(ws + o); o += (size_t)NW * HH * EE * 2;   // 6 MB
    _Float16*       W2tA   = (_Float16*)(ws + o);       o += (size_t)NW * 16 * HH * 2;   // 384 KB
    __hip_bfloat16* Whb    = (__hip_bfloat16*)(ws + o); o += (size_t)MM * HH * 2;        // 32 MB (gate only)
    unsigned*       Wall   = (unsigned*)(ws + o);       o += (size_t)NW * 16 * MM * 4;   // 12 MB (packed f16)
    _Float16*       Vg0    = (_Float16*)(ws + o);       o += (size_t)MM * EE * 2;        // 8 MB (f16 state)

    dim3 blk(256);

    // 0. ALL dtype conversion / weight transposes in one launch
    prep_all<<<12544, blk, 0, stream>>>(V, input, g_W1, g_W2, f_W1, f_W2,
                                        Vb, Xb, gW1t, gW2t, fW1t, W2tA);

    // 1. Gate gemm1: A-in-registers, bf16 output (r14/r16-validated)
    gemm1_areg<<<dim3(MM / 128, HH / 128), blk, 0, stream>>>(Vb, gW1t, g_b1, Whb);
    // 2. Gate gemm2 (K=1024), BN=64 tile (r22-validated), f16 state out
    gemm2_bn64<<<dim3(EE / 64, MM / 128), blk, 0, stream>>>(Whb, gW2t, g_b2, Vg0);

    // 3. All 12 levels' link weights (16x16 MFMA, 40 KB LDS -> 4 blocks/CU)
    f_fused<<<dim3(MM / 128, NW), blk, 0, stream>>>(Xb, fW1t, f_b1, W2tA, f_b2, Wall);

    // 4. ALL 12 chord steps in ONE launch, packed-f16 LDS-resident state
    chord_lds<<<256, dim3(1024), 0, stream>>>((const uint2*)Vg0, Wall, (float4*)out);
}

// Round 26
// 242.868 us; speedup vs baseline: 1.2305x; 1.2305x over previous
//
#include <hip/hip_runtime.h>
#include <hip/hip_bf16.h>
#include <hip/hip_fp16.h>
#include <math.h>

// Problem constants
#define BB 4
#define NN 4096
#define EE 256
#define HH 1024
#define NW 12
#define NL 13
#define MM (BB * NN)   // 16384 rows

typedef __attribute__((ext_vector_type(8))) short short8;   // 8x16b (4 VGPRs)
typedef __attribute__((ext_vector_type(4))) float f32x4;
typedef __attribute__((ext_vector_type(2))) _Float16 h2;    // packed f16 pair
typedef __attribute__((ext_vector_type(8))) _Float16 half8; // f16 MFMA frag

// Fast gelu, f32 scalar: x*sigmoid(1.5957691(x+0.044715x^3)), exp2 form.
__device__ __forceinline__ float gelu_fast(float x) {
    float t = __builtin_fmaf(0.044715f, x * x, 1.0f);
    float e = __builtin_amdgcn_exp2f(-2.3021193f * (x * t));
    return x * __builtin_amdgcn_rcpf(1.0f + e);
}

// Packed-f16 gelu on a pair of f32 inputs -> packed f16 pair bits (r15: -7us).
__device__ __forceinline__ unsigned gelu2_f16(float a, float b) {
    const h2 C1 = {(_Float16)-2.3021193f, (_Float16)-2.3021193f};
    const h2 C2 = {(_Float16)0.044715f, (_Float16)0.044715f};
    const h2 ONE = {(_Float16)1.0f, (_Float16)1.0f};
    h2 x;
    asm("v_cvt_pkrtz_f16_f32 %0, %1, %2" : "=v"(x) : "v"(a), "v"(b));
    h2 x2 = x * x;
    h2 t  = C2 * x2 + ONE;          // v_pk_fma_f16
    h2 z  = (C1 * x) * t;
    __half2 es = h2exp2(__builtin_bit_cast(__half2, z));
    h2 d = ONE + __builtin_bit_cast(h2, es);
    __half2 rs = h2rcp(__builtin_bit_cast(__half2, d));
    h2 y = x * __builtin_bit_cast(h2, rs);
    return __builtin_bit_cast(unsigned, y);
}

// HW packed f32->2xf16 (RTZ), 1 VALU op.
__device__ __forceinline__ h2 cvt_pk_f16(float a, float b) {
    h2 r;
    asm("v_cvt_pkrtz_f16_f32 %0, %1, %2" : "=v"(r) : "v"(a), "v"(b));
    return r;
}

// HW packed f32->2xbf16 (RNE), 1 VALU op.
__device__ __forceinline__ unsigned cvt_pk_bf16(float a, float b) {
    unsigned r;
    asm("v_cvt_pk_bf16_f32 %0, %1, %2" : "=v"(r) : "v"(a), "v"(b));
    return r;
}

__device__ __forceinline__ void load_lds16(const void* g, void* l) {
    __builtin_amdgcn_global_load_lds(
        (const __attribute__((address_space(1))) void*)g,
        (__attribute__((address_space(3))) void*)l, 16, 0, 0);
}

// ---------------------------------------------------------------------------
// Gate gemm2 (K=1024), BN=64 tile, 2 blocks/CU (r22-validated ~16us).
// ---------------------------------------------------------------------------
__global__ __launch_bounds__(256) void gemm2_bn64(
    const __hip_bfloat16* __restrict__ A,   // MM x HH (Whb)
    const __hip_bfloat16* __restrict__ Bt,  // EE x HH (gW2t)
    const float* __restrict__ bias,         // EE
    _Float16* __restrict__ C)               // MM x EE (f16 state)
{
    __shared__ __hip_bfloat16 As[128 * 32];     // 8 KB
    __shared__ __hip_bfloat16 Bs[64 * 32];      // 4 KB

    const int tid = threadIdx.x;
    const int w = tid >> 6, l = tid & 63;
    const int wr = w >> 1, wc = w & 1;          // 2x2; wave tile 64r x 32c
    const int row0 = blockIdx.y * 128;
    const int col0 = blockIdx.x * 64;

    const int c0 = w * 64 + l;
    const int c1 = c0 + 256;
    const __hip_bfloat16* gA0 = A  + (size_t)(row0 + (c0 >> 2)) * HH + (c0 & 3) * 8;
    const __hip_bfloat16* gA1 = A  + (size_t)(row0 + (c1 >> 2)) * HH + (c1 & 3) * 8;
    const __hip_bfloat16* gB0 = Bt + (size_t)(col0 + (c0 >> 2)) * HH + (c0 & 3) * 8;
    char* dA0 = (char*)As + c0 * 16;
    char* dA1 = (char*)As + c1 * 16;
    char* dB0 = (char*)Bs + c0 * 16;

    const int lr = l & 15;
    const int lk = (l >> 4) * 8;

    f32x4 acc[4][2] = {};

    for (int k0 = 0; k0 < HH; k0 += 32) {
        load_lds16(gA0 + k0, dA0);
        load_lds16(gA1 + k0, dA1);
        load_lds16(gB0 + k0, dB0);
        __syncthreads();

        short8 a[4], b[2];
        #pragma unroll
        for (int m = 0; m < 4; ++m)
            a[m] = *(const short8*)&As[(wr * 64 + m * 16 + lr) * 32 + lk];
        #pragma unroll
        for (int n = 0; n < 2; ++n)
            b[n] = *(const short8*)&Bs[(wc * 32 + n * 16 + lr) * 32 + lk];
        #pragma unroll
        for (int m = 0; m < 4; ++m)
            #pragma unroll
            for (int n = 0; n < 2; ++n)
                acc[m][n] = __builtin_amdgcn_mfma_f32_16x16x32_bf16(a[m], b[n], acc[m][n], 0, 0, 0);
        __syncthreads();
    }

    #pragma unroll
    for (int m = 0; m < 4; ++m) {
        #pragma unroll
        for (int n = 0; n < 2; ++n) {
            const int col = col0 + wc * 32 + n * 16 + lr;
            const float bv = bias[col];
            #pragma unroll
            for (int j = 0; j < 4; ++j) {
                const int row = row0 + wr * 64 + m * 16 + (l >> 4) * 4 + j;
                C[(size_t)row * EE + col] = (_Float16)(acc[m][n][j] + bv);
            }
        }
    }
}

// ---------------------------------------------------------------------------
// Gate gemm1, A-in-registers (r14/r16-validated): Wh(bf16) = gelu(Vb@W1+b1).
// ---------------------------------------------------------------------------
__global__ __launch_bounds__(256, 3) void gemm1_areg(
    const __hip_bfloat16* __restrict__ A,     // MM x EE (Vb)
    const __hip_bfloat16* __restrict__ W1t,   // HH x EE
    const float* __restrict__ b1,             // HH
    __hip_bfloat16* __restrict__ Wh)          // MM x HH
{
    __shared__ __hip_bfloat16 Bs[8 * 64 * 32];   // 32 KB [kk][row][32]
    __shared__ __align__(16) char Gb[4][4096];   // per-wave G [32r][64h]

    const int tid = threadIdx.x;
    const int w = tid >> 6, l = tid & 63;
    const int row0 = blockIdx.x * 128;
    const int col0 = blockIdx.y * 128;
    const int lr = l & 15, g = l >> 4, lk = g * 8;

    short8 xf[2][8];
    {
        const __hip_bfloat16* xp0 = A + (size_t)(row0 + w * 32 + lr) * EE + lk;
        #pragma unroll
        for (int kk = 0; kk < 8; ++kk) {
            xf[0][kk] = *(const short8*)(xp0 + kk * 32);
            xf[1][kk] = *(const short8*)(xp0 + 16 * EE + kk * 32);
        }
    }
    char* Gw = Gb[w];

    #pragma unroll
    for (int rstep = 0; rstep < 8; ++rstep) {
        const int c = rstep * 256 + tid;
        load_lds16(W1t + (size_t)(col0 + ((c >> 2) & 63)) * EE + (c >> 8) * 32 + (c & 3) * 8,
                   (char*)Bs + c * 16);
    }
    __syncthreads();

    #pragma unroll 1
    for (int ct = 0; ct < 2; ++ct) {
        f32x4 acc[4][2];
        #pragma unroll
        for (int ni = 0; ni < 4; ++ni) {
            const float4 bv = *(const float4*)&b1[col0 + ct * 64 + ni * 16 + g * 4];
            const f32x4 bi = {bv.x, bv.y, bv.z, bv.w};
            acc[ni][0] = bi;
            acc[ni][1] = bi;
        }
        __builtin_amdgcn_s_setprio(1);
        #pragma unroll
        for (int kk = 0; kk < 8; ++kk) {
            short8 a[4];
            #pragma unroll
            for (int ni = 0; ni < 4; ++ni)
                a[ni] = *(const short8*)((const char*)Bs +
                         (kk * 4096 + ni * 1024 + lr * 64 + g * 16));
            #pragma unroll
            for (int ni = 0; ni < 4; ++ni) {
                acc[ni][0] = __builtin_amdgcn_mfma_f32_16x16x32_bf16(a[ni], xf[0][kk], acc[ni][0], 0, 0, 0);
                acc[ni][1] = __builtin_amdgcn_mfma_f32_16x16x32_bf16(a[ni], xf[1][kk], acc[ni][1], 0, 0, 0);
            }
        }
        __builtin_amdgcn_s_setprio(0);
        __syncthreads();

        if (ct == 0) {
            #pragma unroll
            for (int rstep = 0; rstep < 8; ++rstep) {
                const int c = rstep * 256 + tid;
                load_lds16(W1t + (size_t)(col0 + 64 + ((c >> 2) & 63)) * EE + (c >> 8) * 32 + (c & 3) * 8,
                           (char*)Bs + c * 16);
            }
        }

        // gelu (f32) -> bf16 (cvt_pk) -> wave-private swizzled G
        #pragma unroll
        for (int ni = 0; ni < 4; ++ni) {
            #pragma unroll
            for (int mi = 0; mi < 2; ++mi) {
                const int rloc = mi * 16 + lr;
                const float v0 = gelu_fast(acc[ni][mi][0]);
                const float v1 = gelu_fast(acc[ni][mi][1]);
                const float v2 = gelu_fast(acc[ni][mi][2]);
                const float v3 = gelu_fast(acc[ni][mi][3]);
                uint2 pk;
                pk.x = cvt_pk_bf16(v0, v1);
                pk.y = cvt_pk_bf16(v2, v3);
                const int byte = (rloc * 128 + (ni * 16 + g * 4) * 2) ^ ((rloc & 7) << 4);
                *(uint2*)(Gw + byte) = pk;
            }
        }

        // coalesced store: 4 passes x (8 rows x 128B); G is wave-private
        #pragma unroll
        for (int p = 0; p < 4; ++p) {
            const int rl = p * 8 + (l >> 3);
            const int hb = (l & 7) * 16;
            const uint4 v = *(const uint4*)(Gw + ((rl * 128 + hb) ^ ((rl & 7) << 4)));
            *(uint4*)((char*)(Wh + (size_t)(row0 + w * 32 + rl) * HH + col0 + ct * 64) + hb) = v;
        }
        __syncthreads();
    }
}

// ---------------------------------------------------------------------------
// Fused f-level kernel (r24-validated 135.5us): 16x16 MFMA big GEMM, biasS
// in LDS, 52 KB total, 3 blocks/CU, gelu packed-f16, mini-GEMM f16,
// packed-f16 Wall epilogue. (r25's 40KB/4-block variant spilled at the
// 64-VGPR cap and conflicted on the half-G layout -- reverted.)
// ---------------------------------------------------------------------------
__global__ __launch_bounds__(256, 3) void f_fused(
    const __hip_bfloat16* __restrict__ X,     // MM x EE (bf16)
    const __hip_bfloat16* __restrict__ W1t,   // NW x HH x EE (bf16)
    const float* __restrict__ b1,             // NW x HH
    const _Float16* __restrict__ W2t,         // NW x 16 x HH (f16)
    const float* __restrict__ b2,             // NW x NL
    unsigned* __restrict__ Wall_u)            // [NW*16][MM] packed f16 pairs
{
    __shared__ __hip_bfloat16 Bs[8 * 64 * 32];        // 32 KB [kk][row][32]
    __shared__ __align__(16) char Gb[4][4096];        // per-wave G [32r][64h] f16
    __shared__ float biasS[HH];                       // 4 KB

    const int tid = threadIdx.x;
    const int w = tid >> 6, l = tid & 63;
    const int row0 = blockIdx.x * 128;
    const int m_lv = blockIdx.y;
    const int lr = l & 15;
    const int g  = l >> 4;
    const int lk = g * 8;

    const __hip_bfloat16* W1m = W1t + (size_t)m_lv * HH * EE;

    ((float4*)biasS)[tid] = ((const float4*)(b1 + (size_t)m_lv * HH))[tid];

    short8 xf[2][8];
    {
        const __hip_bfloat16* xp0 = X + (size_t)(row0 + w * 32 + lr) * EE + lk;
        #pragma unroll
        for (int kk = 0; kk < 8; ++kk) {
            xf[0][kk] = *(const short8*)(xp0 + kk * 32);
            xf[1][kk] = *(const short8*)(xp0 + 16 * EE + kk * 32);
        }
    }

    const _Float16* w2p = W2t + ((size_t)m_lv * 16 + lr) * HH + lk;
    char* Gw = Gb[w];

    f32x4 wacc0 = {}, wacc1 = {};

    #pragma unroll
    for (int rstep = 0; rstep < 8; ++rstep) {
        const int c = rstep * 256 + tid;
        load_lds16(W1m + (size_t)((c >> 2) & 63) * EE + (c >> 8) * 32 + (c & 3) * 8,
                   (char*)Bs + c * 16);
    }
    __syncthreads();

    #pragma unroll 1
    for (int ct = 0; ct < 16; ++ct) {
        // acc C-in = bias
        f32x4 acc[4][2];
        #pragma unroll
        for (int ni = 0; ni < 4; ++ni) {
            const float4 bv = *(const float4*)&biasS[ct * 64 + ni * 16 + g * 4];
            const f32x4 bi = {bv.x, bv.y, bv.z, bv.w};
            acc[ni][0] = bi;
            acc[ni][1] = bi;
        }
        __builtin_amdgcn_s_setprio(1);
        #pragma unroll
        for (int kk = 0; kk < 8; ++kk) {
            short8 a[4];
            #pragma unroll
            for (int ni = 0; ni < 4; ++ni)
                a[ni] = *(const short8*)((const char*)Bs +
                         (kk * 4096 + ni * 1024 + lr * 64 + g * 16));
            #pragma unroll
            for (int ni = 0; ni < 4; ++ni) {
                acc[ni][0] = __builtin_amdgcn_mfma_f32_16x16x32_bf16(a[ni], xf[0][kk], acc[ni][0], 0, 0, 0);
                acc[ni][1] = __builtin_amdgcn_mfma_f32_16x16x32_bf16(a[ni], xf[1][kk], acc[ni][1], 0, 0, 0);
            }
        }
        __builtin_amdgcn_s_setprio(0);
        __syncthreads();                       // all waves done reading Bs

        if (ct < 15) {
            const __hip_bfloat16* W1n = W1m + (size_t)(ct + 1) * 64 * EE;
            #pragma unroll
            for (int rstep = 0; rstep < 8; ++rstep) {
                const int c = rstep * 256 + tid;
                load_lds16(W1n + (size_t)((c >> 2) & 63) * EE + (c >> 8) * 32 + (c & 3) * 8,
                           (char*)Bs + c * 16);
            }
        }

        // gelu (packed f16) -> wave-private swizzled G (f16)
        #pragma unroll
        for (int ni = 0; ni < 4; ++ni) {
            #pragma unroll
            for (int mi = 0; mi < 2; ++mi) {
                const int rloc = mi * 16 + lr;
                uint2 pk;
                pk.x = gelu2_f16(acc[ni][mi][0], acc[ni][mi][1]);
                pk.y = gelu2_f16(acc[ni][mi][2], acc[ni][mi][3]);
                const int byte = (rloc * 128 + (ni * 16 + g * 4) * 2) ^ ((rloc & 7) << 4);
                *(uint2*)(Gw + byte) = pk;
            }
        }

        // mini-GEMM (f16): Wall-frag += W2t[ct k-range] x G
        #pragma unroll
        for (int ks2 = 0; ks2 < 2; ++ks2) {
            const half8 aw = *(const half8*)(w2p + ct * 64 + ks2 * 32);
            {
                const int byte = (lr * 128 + (ks2 * 32 + lk) * 2) ^ ((lr & 7) << 4);
                const half8 bg = *(const half8*)(Gw + byte);
                wacc0 = __builtin_amdgcn_mfma_f32_16x16x32_f16(aw, bg, wacc0, 0, 0, 0);
            }
            {
                const int rloc = 16 + lr;
                const int byte = (rloc * 128 + (ks2 * 32 + lk) * 2) ^ ((rloc & 7) << 4);
                const half8 bg = *(const half8*)(Gw + byte);
                wacc1 = __builtin_amdgcn_mfma_f32_16x16x32_f16(aw, bg, wacc1, 0, 0, 0);
            }
        }
        __syncthreads();                       // staging drained; Bs ready
    }

    // epilogue -> Wall_u[(m*16 + lval)*MM + r] as duplicated packed f16
    const float* b2m = b2 + m_lv * NL;
    #pragma unroll
    for (int j = 0; j < 4; ++j) {
        const int lval = g * 4 + j;
        const float bv = (lval < NL) ? b2m[lval] : 0.f;
        unsigned* wp = Wall_u + (size_t)(m_lv * 16 + lval) * MM;
        const float v0 = wacc0[j] + bv;
        const float v1 = wacc1[j] + bv;
        wp[row0 + w * 32 + lr]      = __builtin_bit_cast(unsigned, cvt_pk_f16(v0, v0));
        wp[row0 + w * 32 + 16 + lr] = __builtin_bit_cast(unsigned, cvt_pk_f16(v1, v1));
    }
}

// ---------------------------------------------------------------------------
// One prep kernel for ALL conversions/transposes.
// ---------------------------------------------------------------------------
struct bf4 { __hip_bfloat16 a, b, c, d; };

__device__ __forceinline__ void cvt_body(
    const float* __restrict__ in, __hip_bfloat16* __restrict__ out, int i)
{
    float4 v = ((const float4*)in)[i];
    bf4 o;
    o.a = __float2bfloat16(v.x); o.b = __float2bfloat16(v.y);
    o.c = __float2bfloat16(v.z); o.d = __float2bfloat16(v.w);
    ((bf4*)out)[i] = o;
}

__device__ __forceinline__ void transpose_body(
    const float* __restrict__ inB, __hip_bfloat16* __restrict__ outB,
    int K, int N, int bx, int by, float (*t)[33])
{
    const int n0 = bx * 32, k0 = by * 32;
    const int tx = threadIdx.x & 31, ty = threadIdx.x >> 5;  // 32 x 8
    #pragma unroll
    for (int i = 0; i < 32; i += 8)
        t[ty + i][tx] = inB[(size_t)(k0 + ty + i) * N + n0 + tx];
    __syncthreads();
    #pragma unroll
    for (int i = 0; i < 32; i += 8)
        outB[(size_t)(n0 + ty + i) * K + k0 + tx] = __float2bfloat16(t[tx][ty + i]);
}

__global__ __launch_bounds__(256) void prep_all(
    const float* __restrict__ V, const float* __restrict__ input,
    const float* __restrict__ g_W1, const float* __restrict__ g_W2,
    const float* __restrict__ f_W1, const float* __restrict__ f_W2,
    __hip_bfloat16* __restrict__ Vb, __hip_bfloat16* __restrict__ Xb,
    __hip_bfloat16* __restrict__ gW1t, __hip_bfloat16* __restrict__ gW2t,
    __hip_bfloat16* __restrict__ fW1t, _Float16* __restrict__ W2tA)
{
    __shared__ float t[32][33];
    const int bid = blockIdx.x;
    const int tid = threadIdx.x;

    if (bid < 4096) {
        cvt_body(V, Vb, bid * 256 + tid);
    } else if (bid < 8192) {
        cvt_body(input, Xb, (bid - 4096) * 256 + tid);
    } else if (bid < 8448) {
        const int b2 = bid - 8192;                   // g_W1: grid (32, 8)
        transpose_body(g_W1, gW1t, EE, HH, b2 & 31, b2 >> 5, t);
    } else if (bid < 8704) {
        const int b2 = bid - 8448;                   // g_W2: grid (8, 32)
        transpose_body(g_W2, gW2t, HH, EE, b2 & 7, b2 >> 3, t);
    } else if (bid < 11776) {
        const int b2 = bid - 8704;                   // f_W1: 12 x (32, 8)
        const int z = b2 >> 8, r = b2 & 255;
        transpose_body(f_W1 + (size_t)z * EE * HH, fW1t + (size_t)z * HH * EE,
                       EE, HH, r & 31, r >> 5, t);
    } else {
        const int idx = (bid - 11776) * 256 + tid;   // w2t: NW*16*HH elems, f16
        const int m = idx >> 14;
        const int n = (idx >> 10) & 15;
        const int h = idx & 1023;
        const float v = (n < NL) ? f_W2[((size_t)m * HH + h) * NL + n] : 0.f;
        W2tA[idx] = (_Float16)v;
    }
}

// ---------------------------------------------------------------------------
// ALL 12 chord steps in ONE kernel, PACKED-F16 state resident in LDS
// (r21/r22/r24-validated). Weights pre-packed (duplicated f16 pair per uint).
// ---------------------------------------------------------------------------
__global__ __launch_bounds__(1024, 1) void chord_lds(
    const uint2* __restrict__ Vg,       // MM x 64 (2x packed-f16 per slot)
    const unsigned* __restrict__ Wall_u,// [NW*16][MM] packed f16 pairs
    float4* __restrict__ outF)          // MM x 64 (f32 x4) final output
{
    __shared__ unsigned L[2][2][NN];   // [buf][ch-pair][row]  64 KB

    const int tid = threadIdx.x;       // 0..1023
    const int bid = blockIdx.x;        // 0..255
    const int batch = bid >> 6;
    const int slice = bid & 63;        // 4-channel slice
    const int gbase = batch * NN;

    // init: load own 4 rows from global (f16 x4 per row, already packed)
    #pragma unroll
    for (int i = 0; i < 4; ++i) {
        const int n = tid + i * 1024;
        const uint2 u = Vg[(size_t)(gbase + n) * 64 + slice];
        L[0][0][n] = u.x;
        L[0][1][n] = u.y;
    }
    __syncthreads();

    int cur = 0;
    #pragma unroll 1
    for (int m = 0; m < NW; ++m) {
        const unsigned* wbase = Wall_u + (size_t)m * 16 * MM + gbase;
        const int nxt = cur ^ 1;
        #pragma unroll 1
        for (int i = 0; i < 4; ++i) {
            const int n = tid + i * 1024;
            h2 a01 = __builtin_bit_cast(h2, L[cur][0][n]);
            h2 a23 = __builtin_bit_cast(h2, L[cur][1][n]);
            #pragma unroll
            for (int l = 0; l < NL; ++l) {
                const int off = (l == 0) ? 0 : (1 << (l - 1));
                const int cn = (n + off) & (NN - 1);
                const h2 w2 = __builtin_bit_cast(h2, wbase[(size_t)l * MM + n]);
                const h2 x01 = __builtin_bit_cast(h2, L[cur][0][cn]);
                const h2 x23 = __builtin_bit_cast(h2, L[cur][1][cn]);
                a01 = w2 * x01 + a01;          // v_pk_fma_f16
                a23 = w2 * x23 + a23;
            }
            if (m == NW - 1) {
                float4 o = {(float)a01[0], (float)a01[1],
                            (float)a23[0], (float)a23[1]};
                outF[(size_t)(gbase + n) * 64 + slice] = o;
            } else {
                L[nxt][0][n] = __builtin_bit_cast(unsigned, a01);
                L[nxt][1][n] = __builtin_bit_cast(unsigned, a23);
            }
        }
        __syncthreads();
        cur ^= 1;
    }
}

// ---------------------------------------------------------------------------
extern "C" void kernel_launch(void* const* d_in, const int* in_sizes, int n_in,
                              void* d_out, int out_size, void* d_ws, size_t ws_size,
                              hipStream_t stream)
{
    const float* V      = (const float*)d_in[0];
    const float* input  = (const float*)d_in[1];
    const float* g_W1   = (const float*)d_in[2];
    const float* g_b1   = (const float*)d_in[3];
    const float* g_W2   = (const float*)d_in[4];
    const float* g_b2   = (const float*)d_in[5];
    const float* f_W1   = (const float*)d_in[6];
    const float* f_b1   = (const float*)d_in[7];
    const float* f_W2   = (const float*)d_in[8];
    const float* f_b2   = (const float*)d_in[9];
    float* out = (float*)d_out;

    char* ws = (char*)d_ws;
    size_t o = 0;
    __hip_bfloat16* Vb     = (__hip_bfloat16*)(ws + o); o += (size_t)MM * EE * 2;        // 8 MB
    __hip_bfloat16* Xb     = (__hip_bfloat16*)(ws + o); o += (size_t)MM * EE * 2;        // 8 MB
    __hip_bfloat16* gW1t   = (__hip_bfloat16*)(ws + o); o += (size_t)HH * EE * 2;        // 512 KB
    __hip_bfloat16* gW2t   = (__hip_bfloat16*)(ws + o); o += (size_t)EE * HH * 2;        // 512 KB
    __hip_bfloat16* fW1t   = (__hip_bfloat16*)(ws + o); o += (size_t)NW * HH * EE * 2;   // 6 MB
    _Float16*       W2tA   = (_Float16*)(ws + o);       o += (size_t)NW * 16 * HH * 2;   // 384 KB
    __hip_bfloat16* Whb    = (__hip_bfloat16*)(ws + o); o += (size_t)MM * HH * 2;        // 32 MB (gate only)
    unsigned*       Wall   = (unsigned*)(ws + o);       o += (size_t)NW * 16 * MM * 4;   // 12 MB (packed f16)
    _Float16*       Vg0    = (_Float16*)(ws + o);       o += (size_t)MM * EE * 2;        // 8 MB (f16 state)

    dim3 blk(256);

    // 0. ALL dtype conversion / weight transposes in one launch
    prep_all<<<12544, blk, 0, stream>>>(V, input, g_W1, g_W2, f_W1, f_W2,
                                        Vb, Xb, gW1t, gW2t, fW1t, W2tA);

    // 1. Gate gemm1: A-in-registers, bf16 output (r14/r16-validated)
    gemm1_areg<<<dim3(MM / 128, HH / 128), blk, 0, stream>>>(Vb, gW1t, g_b1, Whb);
    // 2. Gate gemm2 (K=1024), BN=64 tile (r22-validated), f16 state out
    gemm2_bn64<<<dim3(EE / 64, MM / 128), blk, 0, stream>>>(Whb, gW2t, g_b2, Vg0);

    // 3. All 12 levels' link weights (16x16 MFMA, r24-validated 135.5us)
    f_fused<<<dim3(MM / 128, NW), blk, 0, stream>>>(Xb, fW1t, f_b1, W2tA, f_b2, Wall);

    // 4. ALL 12 chord steps in ONE launch, packed-f16 LDS-resident state
    chord_lds<<<256, dim3(1024), 0, stream>>>((const uint2*)Vg0, Wall, (float4*)out);
}